// Round 6
// baseline (279.006 us; speedup 1.0000x reference)
//
#include <hip/hip_runtime.h>
#include <math.h>

#define BATCH 16
#define TWIN 8
#define SEQIN 129
#define DMODEL 192
#define GLEN 2048           // TWIN*256
#define NH 24
#define HD 32
#define DS 128
#define NCC 896             // conv channels (x | B); dt handled separately
#define MTOT (BATCH*GLEN)   // 32768
#define PADK 40             // GEMM LDS row pitch in bf16

typedef __attribute__((ext_vector_type(8))) short bf16x8;
typedef __attribute__((ext_vector_type(4))) float f32x4;

__device__ __forceinline__ float softplus_f(float x){
  return x > 20.f ? x : log1pf(expf(x));
}
__device__ __forceinline__ float silu_f(float x){
  return x / (1.f + __expf(-x));
}
__device__ __forceinline__ unsigned short tobf16(float f){
  union { float f; unsigned u; } v; v.f = f;
  unsigned r = v.u + 0x7FFF + ((v.u >> 16) & 1);
  return (unsigned short)(r >> 16);
}
__device__ __forceinline__ float frombf16(unsigned short u){
  union { unsigned u; float f; } v; v.u = ((unsigned)u) << 16; return v.f;
}

// Build PE-added input (xg fp32 + xh bf16) AND bf16 conv-weight copy (fused:
// in_proj_w rows 768..1663 are contiguous, so wh is a flat cast-copy).
__global__ __launch_bounds__(256) void k_build_xg(const float* __restrict__ in,
    const float* __restrict__ inw, float* __restrict__ xg,
    unsigned short* __restrict__ xh, unsigned short* __restrict__ wh){
  int idx = blockIdx.x*256 + threadIdx.x;
  if (idx < MTOT*DMODEL){
    int d = idx % DMODEL;
    int rest = idx / DMODEL;
    int g = rest % GLEN;
    int b = rest / GLEN;
    int t = g >> 8, s = g & 255;
    float v = 0.f;
    if (s < 128) v = in[((size_t)(b*TWIN + t)*SEQIN + (s+1))*DMODEL + d];
    float div = expf(-(float)(d & ~1) * (logf(10000.f)/(float)DMODEL));
    float ang = (float)t * div;
    v += (d & 1) ? cosf(ang) : sinf(ang);
    xg[idx] = v;
    xh[idx] = tobf16(v);
  } else {
    int j = idx - MTOT*DMODEL;
    if (j < NCC*DMODEL) wh[j] = tobf16(inw[(size_t)768*DMODEL + j]);
  }
}

// MFMA GEMM: projh[m][c] = bf16( sum_k xh[m][k]*wh[c][k] )
__global__ __launch_bounds__(256) void k_gemm_mfma(const unsigned short* __restrict__ xh,
    const unsigned short* __restrict__ wh, unsigned short* __restrict__ projh){
  __shared__ unsigned short As[128*PADK];
  __shared__ unsigned short Bs[128*PADK];
  int tid = threadIdx.x;
  int m0 = blockIdx.x*128, n0 = blockIdx.y*128;
  int wid = tid >> 6, lane = tid & 63;
  int wm = (wid >> 1)*64, wn = (wid & 1)*64;
  int quad = lane >> 4, lm = lane & 15;
  int sr = tid >> 2, sq = tid & 3;
  f32x4 acc[4][4];
  #pragma unroll
  for (int i=0;i<4;i++)
    #pragma unroll
    for (int j=0;j<4;j++) acc[i][j] = (f32x4){0.f,0.f,0.f,0.f};
  for (int k0 = 0; k0 < DMODEL; k0 += 32){
    #pragma unroll
    for (int half=0; half<2; half++){
      int r = sr + half*64;
      *(bf16x8*)&As[r*PADK + sq*8] =
        *(const bf16x8*)&xh[(size_t)(m0+r)*DMODEL + k0 + sq*8];
      *(bf16x8*)&Bs[r*PADK + sq*8] =
        *(const bf16x8*)&wh[(size_t)(n0+r)*DMODEL + k0 + sq*8];
    }
    __syncthreads();
    bf16x8 aF[4], bF[4];
    #pragma unroll
    for (int i=0;i<4;i++){
      aF[i] = *(const bf16x8*)&As[(wm + i*16 + lm)*PADK + quad*8];
      bF[i] = *(const bf16x8*)&Bs[(wn + i*16 + lm)*PADK + quad*8];
    }
    #pragma unroll
    for (int i=0;i<4;i++)
      #pragma unroll
      for (int j=0;j<4;j++)
        acc[i][j] = __builtin_amdgcn_mfma_f32_16x16x32_bf16(aF[i], bF[j], acc[i][j], 0,0,0);
    __syncthreads();
  }
  #pragma unroll
  for (int i=0;i<4;i++){
    #pragma unroll
    for (int r=0;r<4;r++){
      int m = m0 + wm + i*16 + quad*4 + r;
      unsigned short* dst = projh + (size_t)m*NCC + n0 + wn + lm;
      #pragma unroll
      for (int j=0;j<4;j++)
        dst[j*16] = tobf16(acc[i][j][r]);
    }
  }
}

// fp32 GEMM for the 24 dt channels (kept fp32: exponent amplification)
__global__ __launch_bounds__(256) void k_gemm_dt(const float* __restrict__ xg,
    const float* __restrict__ inw, float* __restrict__ dtraw){
  __shared__ float As[16][64];
  __shared__ float Bs[16][64];
  int tid = threadIdx.x;
  int m0 = blockIdx.x*64;
  int ty = tid >> 4, tx = tid & 15;
  int lr = tid >> 2, lq = tid & 3;
  float acc[4][4] = {};
  for (int k0 = 0; k0 < DMODEL; k0 += 16){
    float4 av = *(const float4*)(xg + (size_t)(m0+lr)*DMODEL + k0 + lq*4);
    As[lq*4+0][lr] = av.x; As[lq*4+1][lr] = av.y;
    As[lq*4+2][lr] = av.z; As[lq*4+3][lr] = av.w;
    float4 bv = make_float4(0.f,0.f,0.f,0.f);
    if (lr < NH) bv = *(const float4*)(inw + (size_t)(1792+lr)*DMODEL + k0 + lq*4);
    Bs[lq*4+0][lr] = bv.x; Bs[lq*4+1][lr] = bv.y;
    Bs[lq*4+2][lr] = bv.z; Bs[lq*4+3][lr] = bv.w;
    __syncthreads();
    #pragma unroll
    for (int kk = 0; kk < 16; kk++){
      float4 a = *(const float4*)&As[kk][ty*4];
      float4 bq = *(const float4*)&Bs[kk][tx*4];
      float avr[4] = {a.x, a.y, a.z, a.w};
      float bvr[4] = {bq.x, bq.y, bq.z, bq.w};
      #pragma unroll
      for (int i=0;i<4;i++)
        #pragma unroll
        for (int j=0;j<4;j++)
          acc[i][j] += avr[i]*bvr[j];
    }
    __syncthreads();
  }
  #pragma unroll
  for (int i=0;i<4;i++){
    int m = m0 + ty*4 + i;
    #pragma unroll
    for (int j=0;j<4;j++){
      int n = tx*4 + j;
      if (n < NH) dtraw[(size_t)m*NH + n] = acc[i][j];
    }
  }
}

// Per (b,h): w[g] = exp(csum_total - csum[g]) * dt[g]
__global__ __launch_bounds__(256) void k_scan_w(const float* __restrict__ dtraw,
    const float* __restrict__ dt_bias, const float* __restrict__ A_log,
    float* __restrict__ wbuf){
  int h = blockIdx.x, b = blockIdx.y;
  int tid = threadIdx.x;
  float dtb = dt_bias[h];
  float negA = -expf(A_log[h]);
  float dtv[8], pre[8];
  float run = 0.f;
  size_t base = (size_t)b*GLEN;
  #pragma unroll
  for (int i=0;i<8;i++){
    int g = tid*8 + i;
    float v = dtraw[(base + g)*NH + h];
    float dt = softplus_f(v + dtb);
    run += dt * negA;
    dtv[i] = dt; pre[i] = run;
  }
  __shared__ float s[256];
  float tot_thread = run;
  s[tid] = run;
  __syncthreads();
  for (int off=1; off<256; off<<=1){
    float v = (tid>=off) ? s[tid-off] : 0.f;
    __syncthreads();
    s[tid] += v;
    __syncthreads();
  }
  float total = s[255];
  float excl = s[tid] - tot_thread;
  #pragma unroll
  for (int i=0;i<8;i++){
    int g = tid*8+i;
    float w = expf(total - (excl + pre[i])) * dtv[i];
    wbuf[(base + g)*NH + h] = w;
  }
}

// Fused conv+silu+fold+partial outer product, software-pipelined:
// chunk ch+1's 8 proj rows are prefetched into registers at the top of
// iteration ch and published to the LDS ring only after the barrier that
// retires chunk ch's conv reads (ring slots for rows g0+8..g0+15 alias the
// slots of rows g0-3..g0+3 mod 12, so earlier publication is unsafe).
// Global-load latency thus overlaps conv+fold+outer-product compute.
__global__ __launch_bounds__(256) void k_conv_fuse(const unsigned short* __restrict__ projh,
    const float* __restrict__ conv_w, const float* __restrict__ conv_b,
    const float* __restrict__ wbuf, float* __restrict__ partial){
  int qblk = blockIdx.x;      // 0..63 (32-pos blocks)
  int b = blockIdx.y;
  int tid = threadIdx.x;
  __shared__ unsigned short ring[12*NCC];   // bf16 proj rows, slot = g % 12
  __shared__ float ybuf[8*160];             // [y(32)|Bm(128)] per chunk pos
  __shared__ float wv[8*NH];
  size_t rbase = (size_t)b*GLEN;
  int gblk = qblk*32;
  float acc[4][4] = {};
  int p0 = (tid >> 5)*4, n0 = (tid & 31)*4;
  int cgi = tid >> 5;
  int clane = tid & 31;
  int pq = (clane & 7)*4;     // p-quad this lane folds into

  // prologue: stage chunk 0 (+3 history rows) into ring
  {
    int gstart = gblk - 3, nrows = 11;
    if (gstart < 0){ nrows += gstart; gstart = 0; }
    int nvec = nrows*224;
    for (int idx = tid; idx < nvec; idx += 256){
      int ri = idx / 224, c4 = idx - ri*224;
      int g = gstart + ri;
      *(ushort4*)&ring[(g % 12)*NCC + c4*4] =
        *(const ushort4*)&projh[(rbase + g)*NCC + c4*4];
    }
    if (tid < 8*NH){
      int gi = tid / NH, h = tid - (tid/NH)*NH;
      wv[gi*NH + h] = wbuf[(rbase + gblk + gi)*NH + h];
    }
  }
  __syncthreads();

  for (int ch = 0; ch < 4; ch++){
    int g0 = gblk + ch*8;
    // prefetch chunk ch+1 into registers (7 ushort4/thread, exact)
    ushort4 pre[7];
    float wpre = 0.f;
    if (ch < 3){
      #pragma unroll
      for (int l = 0; l < 7; l++){
        int idx = l*256 + tid;          // 0..1791
        int ri = idx / 224, c4 = idx - ri*224;
        pre[l] = *(const ushort4*)&projh[(rbase + g0 + 8 + ri)*NCC + c4*4];
      }
      if (tid < 8*NH){
        int gi = tid / NH, h = tid - (tid/NH)*NH;
        wpre = wbuf[(rbase + g0 + 8 + gi)*NH + h];
      }
    }
    // conv + silu + fold for chunk ch (reads ring, writes ybuf)
    {
      int g = g0 + cgi;
      float py[4] = {0.f,0.f,0.f,0.f};
      #pragma unroll
      for (int j = 0; j < 7; j++){
        int c = clane*4 + j*128;
        float4 cbv = *(const float4*)&conv_b[c];
        float a0 = cbv.x, a1 = cbv.y, a2 = cbv.z, a3 = cbv.w;
        float4 w0 = *(const float4*)&conv_w[(c+0)*4];
        float4 w1 = *(const float4*)&conv_w[(c+1)*4];
        float4 w2 = *(const float4*)&conv_w[(c+2)*4];
        float4 w3 = *(const float4*)&conv_w[(c+3)*4];
        float cw0[4] = {w0.x,w0.y,w0.z,w0.w};
        float cw1[4] = {w1.x,w1.y,w1.z,w1.w};
        float cw2[4] = {w2.x,w2.y,w2.z,w2.w};
        float cw3[4] = {w3.x,w3.y,w3.z,w3.w};
        #pragma unroll
        for (int k = 0; k < 4; k++){
          int gp = g - 3 + k;
          if (gp >= 0){
            int slot = gp % 12;
            ushort4 pv = *(const ushort4*)&ring[slot*NCC + c];
            a0 += frombf16(pv.x)*cw0[k];
            a1 += frombf16(pv.y)*cw1[k];
            a2 += frombf16(pv.z)*cw2[k];
            a3 += frombf16(pv.w)*cw3[k];
          }
        }
        float s0 = silu_f(a0), s1 = silu_f(a1), s2 = silu_f(a2), s3 = silu_f(a3);
        if (j < 6){
          int h = (clane >> 3) + j*4;
          float wh_ = wv[cgi*NH + h];
          py[0] += wh_*s0; py[1] += wh_*s1; py[2] += wh_*s2; py[3] += wh_*s3;
        } else {
          *(float4*)&ybuf[cgi*160 + 32 + clane*4] = make_float4(s0,s1,s2,s3);
        }
      }
      #pragma unroll
      for (int i=0;i<4;i++){
        py[i] += __shfl_xor(py[i], 8, 64);
        py[i] += __shfl_xor(py[i], 16, 64);
      }
      if (clane < 8)
        *(float4*)&ybuf[cgi*160 + pq] = make_float4(py[0],py[1],py[2],py[3]);
    }
    __syncthreads();   // ybuf visible; all ring/wv reads of chunk ch retired
    // publish prefetched rows into ring (overlaps outer product below)
    if (ch < 3){
      #pragma unroll
      for (int l = 0; l < 7; l++){
        int idx = l*256 + tid;
        int ri = idx / 224, c4 = idx - ri*224;
        *(ushort4*)&ring[((g0 + 8 + ri) % 12)*NCC + c4*4] = pre[l];
      }
      if (tid < 8*NH){
        int gi = tid / NH, h = tid - (tid/NH)*NH;
        wv[gi*NH + h] = wpre;
      }
    }
    // outer-product accumulate from ybuf
    #pragma unroll
    for (int gi = 0; gi < 8; gi++){
      float4 yv = *(const float4*)&ybuf[gi*160 + p0];
      float4 bv = *(const float4*)&ybuf[gi*160 + 32 + n0];
      float ya[4] = {yv.x,yv.y,yv.z,yv.w};
      float ba[4] = {bv.x,bv.y,bv.z,bv.w};
      #pragma unroll
      for (int i=0;i<4;i++)
        #pragma unroll
        for (int j=0;j<4;j++)
          acc[i][j] += ya[i]*ba[j];
    }
    if (ch < 3) __syncthreads();  // ring/wv publication visible for next conv
  }
  size_t pb = ((size_t)(b*64 + qblk))*4096;
  #pragma unroll
  for (int i=0;i<4;i++)
    #pragma unroll
    for (int j=0;j<4;j++)
      partial[pb + (p0+i)*128 + n0+j] = acc[i][j];
}

// Suffix-sum 32-pos partials: feat[b][t] = sum_{q>=8t} partial[b][q]
__global__ __launch_bounds__(256) void k_suffix(const float* __restrict__ partial,
    float* __restrict__ feat){
  int b = blockIdx.y;
  int e = blockIdx.x*256 + threadIdx.x;   // 0..4095
  float s = 0.f;
  for (int q = 63; q >= 0; q--){
    s += partial[((size_t)(b*64 + q))*4096 + e];
    if ((q & 7) == 0)
      feat[((size_t)(b*TWIN + (q >> 3)))*4096 + e] = s;
  }
}

// Boundary corrections for t>0
__global__ __launch_bounds__(256) void k_correct(const unsigned short* __restrict__ projh,
    const float* __restrict__ conv_w, const float* __restrict__ conv_b,
    const float* __restrict__ wbuf, float* __restrict__ feat){
  int t = blockIdx.x + 1, b = blockIdx.y;
  int tid = threadIdx.x;
  __shared__ float xsw[NCC], xsg[NCC];
  __shared__ float wv[NH];
  __shared__ float bufw[3*160], bufg[3*160];
  size_t rbase = (size_t)b*GLEN;
  int g0 = t*256;
  for (int gi=0; gi<3; gi++){
    int g = g0 + gi;
    if (tid < NH) wv[tid] = wbuf[(rbase+g)*NH + tid];
    for (int c = tid; c < NCC; c += 256){
      float aw = conv_b[c], ag = conv_b[c];
      #pragma unroll
      for (int k=0;k<4;k++){
        int gp = g - 3 + k;
        float term = frombf16(projh[(rbase+gp)*NCC + c]) * conv_w[c*4+k];
        ag += term;
        if (gp >= g0) aw += term;
      }
      xsw[c] = silu_f(aw);
      xsg[c] = silu_f(ag);
    }
    __syncthreads();
    if (tid < 32){
      float yw = 0.f, yg = 0.f;
      #pragma unroll
      for (int h=0;h<NH;h++){ yw += wv[h]*xsw[h*32+tid]; yg += wv[h]*xsg[h*32+tid]; }
      bufw[gi*160 + tid] = yw;
      bufg[gi*160 + tid] = yg;
    } else if (tid < 160){
      bufw[gi*160 + tid] = xsw[768 + tid - 32];
      bufg[gi*160 + tid] = xsg[768 + tid - 32];
    }
    __syncthreads();
  }
  int p0 = (tid >> 5) * 4;
  int n0 = (tid & 31) * 4;
  float acc[4][4] = {};
  #pragma unroll
  for (int gi=0; gi<3; gi++){
    float4 ywv = *(const float4*)&bufw[gi*160 + p0];
    float4 bwv = *(const float4*)&bufw[gi*160 + 32 + n0];
    float4 ygv = *(const float4*)&bufg[gi*160 + p0];
    float4 bgv = *(const float4*)&bufg[gi*160 + 32 + n0];
    float yw[4]={ywv.x,ywv.y,ywv.z,ywv.w}, bw[4]={bwv.x,bwv.y,bwv.z,bwv.w};
    float yg[4]={ygv.x,ygv.y,ygv.z,ygv.w}, bg[4]={bgv.x,bgv.y,bgv.z,bgv.w};
    #pragma unroll
    for (int i=0;i<4;i++)
      #pragma unroll
      for (int j=0;j<4;j++)
        acc[i][j] += yw[i]*bw[j] - yg[i]*bg[j];
  }
  size_t fb = (size_t)(b*TWIN + t)*4096;
  #pragma unroll
  for (int i=0;i<4;i++)
    #pragma unroll
    for (int j=0;j<4;j++)
      feat[fb + (p0+i)*128 + n0+j] += acc[i][j];
}

// out[bt][k] = feat[bt] . cls_w[k] + cls_b[k]; one wave per (bt,k)
__global__ __launch_bounds__(256) void k_classifier(const float* __restrict__ feat,
    const float* __restrict__ cls_w, const float* __restrict__ cls_b,
    float* __restrict__ out){
  int bt = blockIdx.x;
  int wave = threadIdx.x >> 6, lane = threadIdx.x & 63;
  int k = blockIdx.y*4 + wave;
  if (k >= 100) return;
  const float* f  = feat  + (size_t)bt*4096;
  const float* wr = cls_w + (size_t)k*4096;
  float s = 0.f;
  #pragma unroll
  for (int j0 = 0; j0 < 4096; j0 += 256){
    int j = j0 + lane*4;
    float4 fv = *(const float4*)(f + j);
    float4 wv = *(const float4*)(wr + j);
    s += fv.x*wv.x + fv.y*wv.y + fv.z*wv.z + fv.w*wv.w;
  }
  #pragma unroll
  for (int off=32; off>0; off>>=1) s += __shfl_down(s, off, 64);
  if (lane==0) out[bt*100 + k] = s + cls_b[k];
}

extern "C" void kernel_launch(void* const* d_in, const int* in_sizes, int n_in,
                              void* d_out, int out_size, void* d_ws, size_t ws_size,
                              hipStream_t stream){
  const float* inputs    = (const float*)d_in[0];
  const float* in_proj_w = (const float*)d_in[1];
  const float* conv_w    = (const float*)d_in[2];
  const float* conv_b    = (const float*)d_in[3];
  const float* dt_bias   = (const float*)d_in[4];
  const float* A_log     = (const float*)d_in[5];
  const float* cls_w     = (const float*)d_in[6];
  const float* cls_b     = (const float*)d_in[7];
  float* out = (float*)d_out;

  float* xg            = (float*)d_ws;                          // MTOT*192 f32
  unsigned short* projh= (unsigned short*)(xg + (size_t)MTOT*DMODEL); // MTOT*896 bf16
  float* dtraw         = (float*)(projh + (size_t)MTOT*NCC);    // MTOT*24 f32
  float* wbuf          = dtraw + (size_t)MTOT*NH;               // MTOT*24 f32
  unsigned short* xh   = (unsigned short*)(wbuf + (size_t)MTOT*NH); // MTOT*192 bf16
  unsigned short* wh   = xh + (size_t)MTOT*DMODEL;              // NCC*192 bf16
  float* partial       = (float*)(wh + (size_t)NCC*DMODEL);     // 1024*4096 f32
  float* feat          = partial + (size_t)1024*4096;           // 128*4096 f32
  size_t need = (size_t)((char*)(feat + (size_t)128*4096) - (char*)d_ws);
  if (ws_size < need) return;

  k_build_xg   <<<((MTOT+NCC)*DMODEL + 255)/256, 256, 0, stream>>>(inputs, in_proj_w, xg, xh, wh);
  k_gemm_mfma  <<<dim3(MTOT/128, NCC/128), 256, 0, stream>>>(xh, wh, projh);
  k_gemm_dt    <<<dim3(MTOT/64, 1), 256, 0, stream>>>(xg, in_proj_w, dtraw);
  k_scan_w     <<<dim3(NH, BATCH), 256, 0, stream>>>(dtraw, dt_bias, A_log, wbuf);
  k_conv_fuse  <<<dim3(64, BATCH), 256, 0, stream>>>(projh, conv_w, conv_b, wbuf, partial);
  k_suffix     <<<dim3(16, BATCH), 256, 0, stream>>>(partial, feat);
  k_correct    <<<dim3(TWIN-1, BATCH), 256, 0, stream>>>(projh, conv_w, conv_b, wbuf, feat);
  k_classifier <<<dim3(BATCH*TWIN, 25), 256, 0, stream>>>(feat, cls_w, cls_b, out);
}

// Round 7
// 274.919 us; speedup vs baseline: 1.0149x; 1.0149x over previous
//
#include <hip/hip_runtime.h>
#include <math.h>

#define BATCH 16
#define TWIN 8
#define SEQIN 129
#define DMODEL 192
#define GLEN 2048           // TWIN*256
#define NH 24
#define HD 32
#define DS 128
#define NCC 896             // conv channels (x | B); dt handled separately
#define MTOT (BATCH*GLEN)   // 32768
#define PADK 40             // GEMM LDS row pitch in bf16

typedef __attribute__((ext_vector_type(8))) short bf16x8;
typedef __attribute__((ext_vector_type(4))) float f32x4;

__device__ __forceinline__ float softplus_f(float x){
  return x > 20.f ? x : log1pf(expf(x));
}
__device__ __forceinline__ float silu_f(float x){
  return x / (1.f + __expf(-x));
}
__device__ __forceinline__ unsigned short tobf16(float f){
  union { float f; unsigned u; } v; v.f = f;
  unsigned r = v.u + 0x7FFF + ((v.u >> 16) & 1);
  return (unsigned short)(r >> 16);
}
__device__ __forceinline__ float frombf16(unsigned short u){
  union { unsigned u; float f; } v; v.u = ((unsigned)u) << 16; return v.f;
}

// Build PE-added input (xg fp32 + xh bf16) AND bf16 conv-weight copy.
__global__ __launch_bounds__(256) void k_build_xg(const float* __restrict__ in,
    const float* __restrict__ inw, float* __restrict__ xg,
    unsigned short* __restrict__ xh, unsigned short* __restrict__ wh){
  int idx = blockIdx.x*256 + threadIdx.x;
  if (idx < MTOT*DMODEL){
    int d = idx % DMODEL;
    int rest = idx / DMODEL;
    int g = rest % GLEN;
    int b = rest / GLEN;
    int t = g >> 8, s = g & 255;
    float v = 0.f;
    if (s < 128) v = in[((size_t)(b*TWIN + t)*SEQIN + (s+1))*DMODEL + d];
    float div = expf(-(float)(d & ~1) * (logf(10000.f)/(float)DMODEL));
    float ang = (float)t * div;
    v += (d & 1) ? cosf(ang) : sinf(ang);
    xg[idx] = v;
    xh[idx] = tobf16(v);
  } else {
    int j = idx - MTOT*DMODEL;
    if (j < NCC*DMODEL) wh[j] = tobf16(inw[(size_t)768*DMODEL + j]);
  }
}

// MFMA GEMM: projh[m][c] = bf16( sum_k xh[m][k]*wh[c][k] )
__global__ __launch_bounds__(256) void k_gemm_mfma(const unsigned short* __restrict__ xh,
    const unsigned short* __restrict__ wh, unsigned short* __restrict__ projh){
  __shared__ unsigned short As[128*PADK];
  __shared__ unsigned short Bs[128*PADK];
  int tid = threadIdx.x;
  int m0 = blockIdx.x*128, n0 = blockIdx.y*128;
  int wid = tid >> 6, lane = tid & 63;
  int wm = (wid >> 1)*64, wn = (wid & 1)*64;
  int quad = lane >> 4, lm = lane & 15;
  int sr = tid >> 2, sq = tid & 3;
  f32x4 acc[4][4];
  #pragma unroll
  for (int i=0;i<4;i++)
    #pragma unroll
    for (int j=0;j<4;j++) acc[i][j] = (f32x4){0.f,0.f,0.f,0.f};
  for (int k0 = 0; k0 < DMODEL; k0 += 32){
    #pragma unroll
    for (int half=0; half<2; half++){
      int r = sr + half*64;
      *(bf16x8*)&As[r*PADK + sq*8] =
        *(const bf16x8*)&xh[(size_t)(m0+r)*DMODEL + k0 + sq*8];
      *(bf16x8*)&Bs[r*PADK + sq*8] =
        *(const bf16x8*)&wh[(size_t)(n0+r)*DMODEL + k0 + sq*8];
    }
    __syncthreads();
    bf16x8 aF[4], bF[4];
    #pragma unroll
    for (int i=0;i<4;i++){
      aF[i] = *(const bf16x8*)&As[(wm + i*16 + lm)*PADK + quad*8];
      bF[i] = *(const bf16x8*)&Bs[(wn + i*16 + lm)*PADK + quad*8];
    }
    #pragma unroll
    for (int i=0;i<4;i++)
      #pragma unroll
      for (int j=0;j<4;j++)
        acc[i][j] = __builtin_amdgcn_mfma_f32_16x16x32_bf16(aF[i], bF[j], acc[i][j], 0,0,0);
    __syncthreads();
  }
  #pragma unroll
  for (int i=0;i<4;i++){
    #pragma unroll
    for (int r=0;r<4;r++){
      int m = m0 + wm + i*16 + quad*4 + r;
      unsigned short* dst = projh + (size_t)m*NCC + n0 + wn + lm;
      #pragma unroll
      for (int j=0;j<4;j++)
        dst[j*16] = tobf16(acc[i][j][r]);
    }
  }
}

// fp32 GEMM for the 24 dt channels (kept fp32: exponent amplification)
__global__ __launch_bounds__(256) void k_gemm_dt(const float* __restrict__ xg,
    const float* __restrict__ inw, float* __restrict__ dtraw){
  __shared__ float As[16][64];
  __shared__ float Bs[16][64];
  int tid = threadIdx.x;
  int m0 = blockIdx.x*64;
  int ty = tid >> 4, tx = tid & 15;
  int lr = tid >> 2, lq = tid & 3;
  float acc[4][4] = {};
  for (int k0 = 0; k0 < DMODEL; k0 += 16){
    float4 av = *(const float4*)(xg + (size_t)(m0+lr)*DMODEL + k0 + lq*4);
    As[lq*4+0][lr] = av.x; As[lq*4+1][lr] = av.y;
    As[lq*4+2][lr] = av.z; As[lq*4+3][lr] = av.w;
    float4 bv = make_float4(0.f,0.f,0.f,0.f);
    if (lr < NH) bv = *(const float4*)(inw + (size_t)(1792+lr)*DMODEL + k0 + lq*4);
    Bs[lq*4+0][lr] = bv.x; Bs[lq*4+1][lr] = bv.y;
    Bs[lq*4+2][lr] = bv.z; Bs[lq*4+3][lr] = bv.w;
    __syncthreads();
    #pragma unroll
    for (int kk = 0; kk < 16; kk++){
      float4 a = *(const float4*)&As[kk][ty*4];
      float4 bq = *(const float4*)&Bs[kk][tx*4];
      float avr[4] = {a.x, a.y, a.z, a.w};
      float bvr[4] = {bq.x, bq.y, bq.z, bq.w};
      #pragma unroll
      for (int i=0;i<4;i++)
        #pragma unroll
        for (int j=0;j<4;j++)
          acc[i][j] += avr[i]*bvr[j];
    }
    __syncthreads();
  }
  #pragma unroll
  for (int i=0;i<4;i++){
    int m = m0 + ty*4 + i;
    #pragma unroll
    for (int j=0;j<4;j++){
      int n = tx*4 + j;
      if (n < NH) dtraw[(size_t)m*NH + n] = acc[i][j];
    }
  }
}

// Per (b,h): w[g] = exp(csum_total - csum[g]) * dt[g]
__global__ __launch_bounds__(256) void k_scan_w(const float* __restrict__ dtraw,
    const float* __restrict__ dt_bias, const float* __restrict__ A_log,
    float* __restrict__ wbuf){
  int h = blockIdx.x, b = blockIdx.y;
  int tid = threadIdx.x;
  float dtb = dt_bias[h];
  float negA = -expf(A_log[h]);
  float dtv[8], pre[8];
  float run = 0.f;
  size_t base = (size_t)b*GLEN;
  #pragma unroll
  for (int i=0;i<8;i++){
    int g = tid*8 + i;
    float v = dtraw[(base + g)*NH + h];
    float dt = softplus_f(v + dtb);
    run += dt * negA;
    dtv[i] = dt; pre[i] = run;
  }
  __shared__ float s[256];
  float tot_thread = run;
  s[tid] = run;
  __syncthreads();
  for (int off=1; off<256; off<<=1){
    float v = (tid>=off) ? s[tid-off] : 0.f;
    __syncthreads();
    s[tid] += v;
    __syncthreads();
  }
  float total = s[255];
  float excl = s[tid] - tot_thread;
  #pragma unroll
  for (int i=0;i<8;i++){
    int g = tid*8+i;
    float w = expf(total - (excl + pre[i])) * dtv[i];
    wbuf[(base + g)*NH + h] = w;
  }
}

// One wave per position: conv+silu+head-fold, all in registers/shuffles.
// Lane l owns channel pair c = 2l + 128k (k=0..6). h = (l>>4)+4k, p = 2(l&15).
// k==6 is the B-channel group (c>=768 -> n = 2l).
__global__ __launch_bounds__(256) void k_fold(const unsigned short* __restrict__ projh,
    const float* __restrict__ conv_w, const float* __restrict__ conv_b,
    const float* __restrict__ wbuf, float* __restrict__ yB){
  int wave = threadIdx.x >> 6, lane = threadIdx.x & 63;
  int g = blockIdx.x*4 + wave;
  int b = blockIdx.y;
  size_t rbase = (size_t)b*GLEN;
  size_t row = rbase + g;
  float wreg = (lane < NH) ? wbuf[row*NH + lane] : 0.f;
  float py0 = 0.f, py1 = 0.f, b0 = 0.f, b1 = 0.f;
  #pragma unroll
  for (int k = 0; k < 7; k++){
    int c = 2*lane + 128*k;
    float2 cb = *(const float2*)&conv_b[c];
    float a0 = cb.x, a1 = cb.y;
    float4 w0 = *(const float4*)&conv_w[c*4];
    float4 w1 = *(const float4*)&conv_w[(c+1)*4];
    float cw0[4] = {w0.x,w0.y,w0.z,w0.w};
    float cw1[4] = {w1.x,w1.y,w1.z,w1.w};
    #pragma unroll
    for (int t = 0; t < 4; t++){
      int gp = g - 3 + t;
      if (gp >= 0){
        ushort2 pv = *(const ushort2*)&projh[(rbase+gp)*NCC + c];
        a0 += frombf16(pv.x)*cw0[t];
        a1 += frombf16(pv.y)*cw1[t];
      }
    }
    float s0 = silu_f(a0), s1 = silu_f(a1);
    if (k < 6){
      float wh_ = __shfl(wreg, (lane>>4) + 4*k, 64);
      py0 += wh_*s0; py1 += wh_*s1;
    } else { b0 = s0; b1 = s1; }
  }
  py0 += __shfl_xor(py0, 16, 64); py0 += __shfl_xor(py0, 32, 64);
  py1 += __shfl_xor(py1, 16, 64); py1 += __shfl_xor(py1, 32, 64);
  float* dst = yB + row*160;
  if (lane < 16) *(float2*)&dst[2*lane] = make_float2(py0, py1);
  *(float2*)&dst[32 + 2*lane] = make_float2(b0, b1);
}

// Chunk partials: partial[b][t][sub][32][128] over 64 positions each
__global__ __launch_bounds__(256) void k_partial(const float* __restrict__ yB,
    float* __restrict__ partial){
  int t = blockIdx.x & 7, b = blockIdx.x >> 3, sub = blockIdx.y;
  int tid = threadIdx.x;
  __shared__ float buf[8*160];
  int p0 = (tid >> 5) * 4;
  int n0 = (tid & 31) * 4;
  float acc[4][4] = {};
  size_t rbase = (size_t)b*GLEN;
  int gstart = t*256 + sub*64;
  for (int gb = gstart; gb < gstart+64; gb += 8){
    for (int idx = tid; idx < 8*160; idx += 256)
      buf[idx] = yB[(rbase+gb)*160 + idx];
    __syncthreads();
    #pragma unroll
    for (int gi=0; gi<8; gi++){
      float4 yv = *(const float4*)&buf[gi*160 + p0];
      float4 bv = *(const float4*)&buf[gi*160 + 32 + n0];
      float ya[4] = {yv.x,yv.y,yv.z,yv.w};
      float ba[4] = {bv.x,bv.y,bv.z,bv.w};
      #pragma unroll
      for (int i=0;i<4;i++)
        #pragma unroll
        for (int j=0;j<4;j++)
          acc[i][j] += ya[i]*ba[j];
    }
    __syncthreads();
  }
  size_t pb = (((size_t)(b*TWIN + t))*4 + sub)*4096;
  #pragma unroll
  for (int i=0;i<4;i++)
    #pragma unroll
    for (int j=0;j<4;j++)
      partial[pb + (p0+i)*128 + n0+j] = acc[i][j];
}

// Suffix-sum partials over t: feat[b][t] = sum_{t'>=t} sum_sub partial[b][t'][sub]
__global__ __launch_bounds__(256) void k_suffix(const float* __restrict__ partial,
    float* __restrict__ feat){
  int b = blockIdx.y;
  int e = blockIdx.x*256 + threadIdx.x;   // 0..4095
  float s = 0.f;
  for (int t = TWIN-1; t >= 0; t--){
    size_t pb = ((size_t)(b*TWIN + t))*4*4096;
    #pragma unroll
    for (int sub=0; sub<4; sub++) s += partial[pb + sub*4096 + e];
    feat[((size_t)(b*TWIN + t))*4096 + e] = s;
  }
}

// Boundary corrections for t>0
__global__ __launch_bounds__(256) void k_correct(const unsigned short* __restrict__ projh,
    const float* __restrict__ conv_w, const float* __restrict__ conv_b,
    const float* __restrict__ wbuf, float* __restrict__ feat){
  int t = blockIdx.x + 1, b = blockIdx.y;
  int tid = threadIdx.x;
  __shared__ float xsw[NCC], xsg[NCC];
  __shared__ float wv[NH];
  __shared__ float bufw[3*160], bufg[3*160];
  size_t rbase = (size_t)b*GLEN;
  int g0 = t*256;
  for (int gi=0; gi<3; gi++){
    int g = g0 + gi;
    if (tid < NH) wv[tid] = wbuf[(rbase+g)*NH + tid];
    for (int c = tid; c < NCC; c += 256){
      float aw = conv_b[c], ag = conv_b[c];
      #pragma unroll
      for (int k=0;k<4;k++){
        int gp = g - 3 + k;
        float term = frombf16(projh[(rbase+gp)*NCC + c]) * conv_w[c*4+k];
        ag += term;
        if (gp >= g0) aw += term;
      }
      xsw[c] = silu_f(aw);
      xsg[c] = silu_f(ag);
    }
    __syncthreads();
    if (tid < 32){
      float yw = 0.f, yg = 0.f;
      #pragma unroll
      for (int h=0;h<NH;h++){ yw += wv[h]*xsw[h*32+tid]; yg += wv[h]*xsg[h*32+tid]; }
      bufw[gi*160 + tid] = yw;
      bufg[gi*160 + tid] = yg;
    } else if (tid < 160){
      bufw[gi*160 + tid] = xsw[768 + tid - 32];
      bufg[gi*160 + tid] = xsg[768 + tid - 32];
    }
    __syncthreads();
  }
  int p0 = (tid >> 5) * 4;
  int n0 = (tid & 31) * 4;
  float acc[4][4] = {};
  #pragma unroll
  for (int gi=0; gi<3; gi++){
    float4 ywv = *(const float4*)&bufw[gi*160 + p0];
    float4 bwv = *(const float4*)&bufw[gi*160 + 32 + n0];
    float4 ygv = *(const float4*)&bufg[gi*160 + p0];
    float4 bgv = *(const float4*)&bufg[gi*160 + 32 + n0];
    float yw[4]={ywv.x,ywv.y,ywv.z,ywv.w}, bw[4]={bwv.x,bwv.y,bwv.z,bwv.w};
    float yg[4]={ygv.x,ygv.y,ygv.z,ygv.w}, bg[4]={bgv.x,bgv.y,bgv.z,bgv.w};
    #pragma unroll
    for (int i=0;i<4;i++)
      #pragma unroll
      for (int j=0;j<4;j++)
        acc[i][j] += yw[i]*bw[j] - yg[i]*bg[j];
  }
  size_t fb = (size_t)(b*TWIN + t)*4096;
  #pragma unroll
  for (int i=0;i<4;i++)
    #pragma unroll
    for (int j=0;j<4;j++)
      feat[fb + (p0+i)*128 + n0+j] += acc[i][j];
}

// out[bt][k] = feat[bt] . cls_w[k] + cls_b[k]; one wave per (bt,k)
__global__ __launch_bounds__(256) void k_classifier(const float* __restrict__ feat,
    const float* __restrict__ cls_w, const float* __restrict__ cls_b,
    float* __restrict__ out){
  int bt = blockIdx.x;
  int wave = threadIdx.x >> 6, lane = threadIdx.x & 63;
  int k = blockIdx.y*4 + wave;
  if (k >= 100) return;
  const float* f  = feat  + (size_t)bt*4096;
  const float* wr = cls_w + (size_t)k*4096;
  float s = 0.f;
  #pragma unroll
  for (int j0 = 0; j0 < 4096; j0 += 256){
    int j = j0 + lane*4;
    float4 fv = *(const float4*)(f + j);
    float4 wv = *(const float4*)(wr + j);
    s += fv.x*wv.x + fv.y*wv.y + fv.z*wv.z + fv.w*wv.w;
  }
  #pragma unroll
  for (int off=32; off>0; off>>=1) s += __shfl_down(s, off, 64);
  if (lane==0) out[bt*100 + k] = s + cls_b[k];
}

extern "C" void kernel_launch(void* const* d_in, const int* in_sizes, int n_in,
                              void* d_out, int out_size, void* d_ws, size_t ws_size,
                              hipStream_t stream){
  const float* inputs    = (const float*)d_in[0];
  const float* in_proj_w = (const float*)d_in[1];
  const float* conv_w    = (const float*)d_in[2];
  const float* conv_b    = (const float*)d_in[3];
  const float* dt_bias   = (const float*)d_in[4];
  const float* A_log     = (const float*)d_in[5];
  const float* cls_w     = (const float*)d_in[6];
  const float* cls_b     = (const float*)d_in[7];
  float* out = (float*)d_out;

  float* xg            = (float*)d_ws;                          // MTOT*192 f32
  unsigned short* projh= (unsigned short*)(xg + (size_t)MTOT*DMODEL); // MTOT*896 bf16
  float* dtraw         = (float*)(projh + (size_t)MTOT*NCC);    // MTOT*24 f32
  float* wbuf          = dtraw + (size_t)MTOT*NH;               // MTOT*24 f32
  unsigned short* xh   = (unsigned short*)(wbuf + (size_t)MTOT*NH); // MTOT*192 bf16
  unsigned short* wh   = xh + (size_t)MTOT*DMODEL;              // NCC*192 bf16
  float* yB            = (float*)(wh + (size_t)NCC*DMODEL);     // MTOT*160 f32
  float* partial       = yB + (size_t)MTOT*160;                 // 512*4096 f32
  float* feat          = partial + (size_t)512*4096;            // 128*4096 f32
  size_t need = (size_t)((char*)(feat + (size_t)128*4096) - (char*)d_ws);
  if (ws_size < need) return;

  k_build_xg   <<<((MTOT+NCC)*DMODEL + 255)/256, 256, 0, stream>>>(inputs, in_proj_w, xg, xh, wh);
  k_gemm_mfma  <<<dim3(MTOT/128, NCC/128), 256, 0, stream>>>(xh, wh, projh);
  k_gemm_dt    <<<dim3(MTOT/64, 1), 256, 0, stream>>>(xg, in_proj_w, dtraw);
  k_scan_w     <<<dim3(NH, BATCH), 256, 0, stream>>>(dtraw, dt_bias, A_log, wbuf);
  k_fold       <<<dim3(GLEN/4, BATCH), 256, 0, stream>>>(projh, conv_w, conv_b, wbuf, yB);
  k_partial    <<<dim3(BATCH*TWIN, 4), 256, 0, stream>>>(yB, partial);
  k_suffix     <<<dim3(16, BATCH), 256, 0, stream>>>(partial, feat);
  k_correct    <<<dim3(TWIN-1, BATCH), 256, 0, stream>>>(projh, conv_w, conv_b, wbuf, feat);
  k_classifier <<<dim3(BATCH*TWIN, 25), 256, 0, stream>>>(feat, cls_w, cls_b, out);
}

// Round 8
// 220.886 us; speedup vs baseline: 1.2631x; 1.2446x over previous
//
#include <hip/hip_runtime.h>
#include <math.h>

#define BATCH 16
#define TWIN 8
#define SEQIN 129
#define DMODEL 192
#define GLEN 2048           // TWIN*256
#define NH 24
#define HD 32
#define DS 128
#define NCC 896             // conv channels (x | B); dt handled separately
#define MTOT (BATCH*GLEN)   // 32768
#define PADK 40             // GEMM LDS row pitch in bf16

typedef __attribute__((ext_vector_type(8))) short bf16x8;
typedef __attribute__((ext_vector_type(4))) float f32x4;

__device__ __forceinline__ float softplus_f(float x){
  return x > 20.f ? x : log1pf(expf(x));
}
__device__ __forceinline__ float silu_f(float x){
  return x / (1.f + __expf(-x));
}
__device__ __forceinline__ unsigned short tobf16(float f){
  union { float f; unsigned u; } v; v.f = f;
  unsigned r = v.u + 0x7FFF + ((v.u >> 16) & 1);
  return (unsigned short)(r >> 16);
}
__device__ __forceinline__ float frombf16(unsigned short u){
  union { unsigned u; float f; } v; v.u = ((unsigned)u) << 16; return v.f;
}

// Build PE-added input (xg fp32 + xh bf16) AND bf16 conv-weight copy.
__global__ __launch_bounds__(256) void k_build_xg(const float* __restrict__ in,
    const float* __restrict__ inw, float* __restrict__ xg,
    unsigned short* __restrict__ xh, unsigned short* __restrict__ wh){
  int idx = blockIdx.x*256 + threadIdx.x;
  if (idx < MTOT*DMODEL){
    int d = idx % DMODEL;
    int rest = idx / DMODEL;
    int g = rest % GLEN;
    int b = rest / GLEN;
    int t = g >> 8, s = g & 255;
    float v = 0.f;
    if (s < 128) v = in[((size_t)(b*TWIN + t)*SEQIN + (s+1))*DMODEL + d];
    float div = expf(-(float)(d & ~1) * (logf(10000.f)/(float)DMODEL));
    float ang = (float)t * div;
    v += (d & 1) ? cosf(ang) : sinf(ang);
    xg[idx] = v;
    xh[idx] = tobf16(v);
  } else {
    int j = idx - MTOT*DMODEL;
    if (j < NCC*DMODEL) wh[j] = tobf16(inw[(size_t)768*DMODEL + j]);
  }
}

// MFMA GEMM: projh[m][c] = bf16( sum_k xh[m][k]*wh[c][k] )
__global__ __launch_bounds__(256) void k_gemm_mfma(const unsigned short* __restrict__ xh,
    const unsigned short* __restrict__ wh, unsigned short* __restrict__ projh){
  __shared__ unsigned short As[128*PADK];
  __shared__ unsigned short Bs[128*PADK];
  int tid = threadIdx.x;
  int m0 = blockIdx.x*128, n0 = blockIdx.y*128;
  int wid = tid >> 6, lane = tid & 63;
  int wm = (wid >> 1)*64, wn = (wid & 1)*64;
  int quad = lane >> 4, lm = lane & 15;
  int sr = tid >> 2, sq = tid & 3;
  f32x4 acc[4][4];
  #pragma unroll
  for (int i=0;i<4;i++)
    #pragma unroll
    for (int j=0;j<4;j++) acc[i][j] = (f32x4){0.f,0.f,0.f,0.f};
  for (int k0 = 0; k0 < DMODEL; k0 += 32){
    #pragma unroll
    for (int half=0; half<2; half++){
      int r = sr + half*64;
      *(bf16x8*)&As[r*PADK + sq*8] =
        *(const bf16x8*)&xh[(size_t)(m0+r)*DMODEL + k0 + sq*8];
      *(bf16x8*)&Bs[r*PADK + sq*8] =
        *(const bf16x8*)&wh[(size_t)(n0+r)*DMODEL + k0 + sq*8];
    }
    __syncthreads();
    bf16x8 aF[4], bF[4];
    #pragma unroll
    for (int i=0;i<4;i++){
      aF[i] = *(const bf16x8*)&As[(wm + i*16 + lm)*PADK + quad*8];
      bF[i] = *(const bf16x8*)&Bs[(wn + i*16 + lm)*PADK + quad*8];
    }
    #pragma unroll
    for (int i=0;i<4;i++)
      #pragma unroll
      for (int j=0;j<4;j++)
        acc[i][j] = __builtin_amdgcn_mfma_f32_16x16x32_bf16(aF[i], bF[j], acc[i][j], 0,0,0);
    __syncthreads();
  }
  #pragma unroll
  for (int i=0;i<4;i++){
    #pragma unroll
    for (int r=0;r<4;r++){
      int m = m0 + wm + i*16 + quad*4 + r;
      unsigned short* dst = projh + (size_t)m*NCC + n0 + wn + lm;
      #pragma unroll
      for (int j=0;j<4;j++)
        dst[j*16] = tobf16(acc[i][j][r]);
    }
  }
}

// fp32 GEMM for the 24 dt channels (kept fp32: exponent amplification)
__global__ __launch_bounds__(256) void k_gemm_dt(const float* __restrict__ xg,
    const float* __restrict__ inw, float* __restrict__ dtraw){
  __shared__ float As[16][64];
  __shared__ float Bs[16][64];
  int tid = threadIdx.x;
  int m0 = blockIdx.x*64;
  int ty = tid >> 4, tx = tid & 15;
  int lr = tid >> 2, lq = tid & 3;
  float acc[4][4] = {};
  for (int k0 = 0; k0 < DMODEL; k0 += 16){
    float4 av = *(const float4*)(xg + (size_t)(m0+lr)*DMODEL + k0 + lq*4);
    As[lq*4+0][lr] = av.x; As[lq*4+1][lr] = av.y;
    As[lq*4+2][lr] = av.z; As[lq*4+3][lr] = av.w;
    float4 bv = make_float4(0.f,0.f,0.f,0.f);
    if (lr < NH) bv = *(const float4*)(inw + (size_t)(1792+lr)*DMODEL + k0 + lq*4);
    Bs[lq*4+0][lr] = bv.x; Bs[lq*4+1][lr] = bv.y;
    Bs[lq*4+2][lr] = bv.z; Bs[lq*4+3][lr] = bv.w;
    __syncthreads();
    #pragma unroll
    for (int kk = 0; kk < 16; kk++){
      float4 a = *(const float4*)&As[kk][ty*4];
      float4 bq = *(const float4*)&Bs[kk][tx*4];
      float avr[4] = {a.x, a.y, a.z, a.w};
      float bvr[4] = {bq.x, bq.y, bq.z, bq.w};
      #pragma unroll
      for (int i=0;i<4;i++)
        #pragma unroll
        for (int j=0;j<4;j++)
          acc[i][j] += avr[i]*bvr[j];
    }
    __syncthreads();
  }
  #pragma unroll
  for (int i=0;i<4;i++){
    int m = m0 + ty*4 + i;
    #pragma unroll
    for (int j=0;j<4;j++){
      int n = tx*4 + j;
      if (n < NH) dtraw[(size_t)m*NH + n] = acc[i][j];
    }
  }
}

// Per (b,h): w[g] = exp(csum_total - csum[g]) * dt[g]
__global__ __launch_bounds__(256) void k_scan_w(const float* __restrict__ dtraw,
    const float* __restrict__ dt_bias, const float* __restrict__ A_log,
    float* __restrict__ wbuf){
  int h = blockIdx.x, b = blockIdx.y;
  int tid = threadIdx.x;
  float dtb = dt_bias[h];
  float negA = -expf(A_log[h]);
  float dtv[8], pre[8];
  float run = 0.f;
  size_t base = (size_t)b*GLEN;
  #pragma unroll
  for (int i=0;i<8;i++){
    int g = tid*8 + i;
    float v = dtraw[(base + g)*NH + h];
    float dt = softplus_f(v + dtb);
    run += dt * negA;
    dtv[i] = dt; pre[i] = run;
  }
  __shared__ float s[256];
  float tot_thread = run;
  s[tid] = run;
  __syncthreads();
  for (int off=1; off<256; off<<=1){
    float v = (tid>=off) ? s[tid-off] : 0.f;
    __syncthreads();
    s[tid] += v;
    __syncthreads();
  }
  float total = s[255];
  float excl = s[tid] - tot_thread;
  #pragma unroll
  for (int i=0;i<8;i++){
    int g = tid*8+i;
    float w = expf(total - (excl + pre[i])) * dtv[i];
    wbuf[(base + g)*NH + h] = w;
  }
}

// One wave per 8-position strip: conv history kept in registers, conv weights
// loaded once per wave. Per position only 7 projh loads + 1 wbuf load.
// Lane l owns channel pair c = 2l + 128k (k=0..6). h = (l>>4)+4k.
__global__ __launch_bounds__(256) void k_fold(const unsigned short* __restrict__ projh,
    const float* __restrict__ conv_w, const float* __restrict__ conv_b,
    const float* __restrict__ wbuf, float* __restrict__ yB){
  int wave = threadIdx.x >> 6, lane = threadIdx.x & 63;
  int strip = blockIdx.x*4 + wave;     // 0..255
  int b = blockIdx.y;
  int g0 = strip*8;
  size_t rbase = (size_t)b*GLEN;
  // conv weights/biases: once per wave
  float cb[7][2], cw[7][2][4];
  #pragma unroll
  for (int k=0;k<7;k++){
    int c = 2*lane + 128*k;
    float2 t = *(const float2*)&conv_b[c];
    cb[k][0]=t.x; cb[k][1]=t.y;
    float4 w0 = *(const float4*)&conv_w[c*4];
    float4 w1 = *(const float4*)&conv_w[(c+1)*4];
    cw[k][0][0]=w0.x; cw[k][0][1]=w0.y; cw[k][0][2]=w0.z; cw[k][0][3]=w0.w;
    cw[k][1][0]=w1.x; cw[k][1][1]=w1.y; cw[k][1][2]=w1.z; cw[k][1][3]=w1.w;
  }
  // history rows g0-3..g0-1 (zero at sequence start)
  float h0[7][2], h1[7][2], h2[7][2];
  #pragma unroll
  for (int k=0;k<7;k++){
    h0[k][0]=h0[k][1]=h1[k][0]=h1[k][1]=h2[k][0]=h2[k][1]=0.f;
  }
  if (g0 >= 3){
    #pragma unroll
    for (int k=0;k<7;k++){
      int c = 2*lane + 128*k;
      ushort2 p0 = *(const ushort2*)&projh[(rbase+g0-3)*NCC + c];
      ushort2 p1 = *(const ushort2*)&projh[(rbase+g0-2)*NCC + c];
      ushort2 p2 = *(const ushort2*)&projh[(rbase+g0-1)*NCC + c];
      h0[k][0]=frombf16(p0.x); h0[k][1]=frombf16(p0.y);
      h1[k][0]=frombf16(p1.x); h1[k][1]=frombf16(p1.y);
      h2[k][0]=frombf16(p2.x); h2[k][1]=frombf16(p2.y);
    }
  }
  #pragma unroll
  for (int i=0;i<8;i++){
    size_t row = rbase + g0 + i;
    float wreg = (lane < NH) ? wbuf[row*NH + lane] : 0.f;
    float cur[7][2];
    #pragma unroll
    for (int k=0;k<7;k++){
      int c = 2*lane + 128*k;
      ushort2 pv = *(const ushort2*)&projh[row*NCC + c];
      cur[k][0]=frombf16(pv.x); cur[k][1]=frombf16(pv.y);
    }
    float py0=0.f, py1=0.f, b0v=0.f, b1v=0.f;
    #pragma unroll
    for (int k=0;k<7;k++){
      float a0 = cb[k][0] + h0[k][0]*cw[k][0][0] + h1[k][0]*cw[k][0][1]
                          + h2[k][0]*cw[k][0][2] + cur[k][0]*cw[k][0][3];
      float a1 = cb[k][1] + h0[k][1]*cw[k][1][0] + h1[k][1]*cw[k][1][1]
                          + h2[k][1]*cw[k][1][2] + cur[k][1]*cw[k][1][3];
      float s0 = silu_f(a0), s1 = silu_f(a1);
      if (k < 6){
        float wh_ = __shfl(wreg, (lane>>4) + 4*k, 64);
        py0 += wh_*s0; py1 += wh_*s1;
      } else { b0v = s0; b1v = s1; }
    }
    py0 += __shfl_xor(py0, 16, 64); py0 += __shfl_xor(py0, 32, 64);
    py1 += __shfl_xor(py1, 16, 64); py1 += __shfl_xor(py1, 32, 64);
    float* dst = yB + row*160;
    if (lane < 16) *(float2*)&dst[2*lane] = make_float2(py0, py1);
    *(float2*)&dst[32 + 2*lane] = make_float2(b0v, b1v);
    // roll history (register renames under full unroll)
    #pragma unroll
    for (int k=0;k<7;k++){
      h0[k][0]=h1[k][0]; h0[k][1]=h1[k][1];
      h1[k][0]=h2[k][0]; h1[k][1]=h2[k][1];
      h2[k][0]=cur[k][0]; h2[k][1]=cur[k][1];
    }
  }
}

// Chunk partials: partial[b][t][sub][32][128] over 64 positions each
__global__ __launch_bounds__(256) void k_partial(const float* __restrict__ yB,
    float* __restrict__ partial){
  int t = blockIdx.x & 7, b = blockIdx.x >> 3, sub = blockIdx.y;
  int tid = threadIdx.x;
  __shared__ float buf[8*160];
  int p0 = (tid >> 5) * 4;
  int n0 = (tid & 31) * 4;
  float acc[4][4] = {};
  size_t rbase = (size_t)b*GLEN;
  int gstart = t*256 + sub*64;
  for (int gb = gstart; gb < gstart+64; gb += 8){
    for (int idx = tid; idx < 8*160; idx += 256)
      buf[idx] = yB[(rbase+gb)*160 + idx];
    __syncthreads();
    #pragma unroll
    for (int gi=0; gi<8; gi++){
      float4 yv = *(const float4*)&buf[gi*160 + p0];
      float4 bv = *(const float4*)&buf[gi*160 + 32 + n0];
      float ya[4] = {yv.x,yv.y,yv.z,yv.w};
      float ba[4] = {bv.x,bv.y,bv.z,bv.w};
      #pragma unroll
      for (int i=0;i<4;i++)
        #pragma unroll
        for (int j=0;j<4;j++)
          acc[i][j] += ya[i]*ba[j];
    }
    __syncthreads();
  }
  size_t pb = (((size_t)(b*TWIN + t))*4 + sub)*4096;
  #pragma unroll
  for (int i=0;i<4;i++)
    #pragma unroll
    for (int j=0;j<4;j++)
      partial[pb + (p0+i)*128 + n0+j] = acc[i][j];
}

// Suffix-sum partials over t
__global__ __launch_bounds__(256) void k_suffix(const float* __restrict__ partial,
    float* __restrict__ feat){
  int b = blockIdx.y;
  int e = blockIdx.x*256 + threadIdx.x;   // 0..4095
  float s = 0.f;
  for (int t = TWIN-1; t >= 0; t--){
    size_t pb = ((size_t)(b*TWIN + t))*4*4096;
    #pragma unroll
    for (int sub=0; sub<4; sub++) s += partial[pb + sub*4096 + e];
    feat[((size_t)(b*TWIN + t))*4096 + e] = s;
  }
}

// Boundary corrections for t>0
__global__ __launch_bounds__(256) void k_correct(const unsigned short* __restrict__ projh,
    const float* __restrict__ conv_w, const float* __restrict__ conv_b,
    const float* __restrict__ wbuf, float* __restrict__ feat){
  int t = blockIdx.x + 1, b = blockIdx.y;
  int tid = threadIdx.x;
  __shared__ float xsw[NCC], xsg[NCC];
  __shared__ float wv[NH];
  __shared__ float bufw[3*160], bufg[3*160];
  size_t rbase = (size_t)b*GLEN;
  int g0 = t*256;
  for (int gi=0; gi<3; gi++){
    int g = g0 + gi;
    if (tid < NH) wv[tid] = wbuf[(rbase+g)*NH + tid];
    for (int c = tid; c < NCC; c += 256){
      float aw = conv_b[c], ag = conv_b[c];
      #pragma unroll
      for (int k=0;k<4;k++){
        int gp = g - 3 + k;
        float term = frombf16(projh[(rbase+gp)*NCC + c]) * conv_w[c*4+k];
        ag += term;
        if (gp >= g0) aw += term;
      }
      xsw[c] = silu_f(aw);
      xsg[c] = silu_f(ag);
    }
    __syncthreads();
    if (tid < 32){
      float yw = 0.f, yg = 0.f;
      #pragma unroll
      for (int h=0;h<NH;h++){ yw += wv[h]*xsw[h*32+tid]; yg += wv[h]*xsg[h*32+tid]; }
      bufw[gi*160 + tid] = yw;
      bufg[gi*160 + tid] = yg;
    } else if (tid < 160){
      bufw[gi*160 + tid] = xsw[768 + tid - 32];
      bufg[gi*160 + tid] = xsg[768 + tid - 32];
    }
    __syncthreads();
  }
  int p0 = (tid >> 5) * 4;
  int n0 = (tid & 31) * 4;
  float acc[4][4] = {};
  #pragma unroll
  for (int gi=0; gi<3; gi++){
    float4 ywv = *(const float4*)&bufw[gi*160 + p0];
    float4 bwv = *(const float4*)&bufw[gi*160 + 32 + n0];
    float4 ygv = *(const float4*)&bufg[gi*160 + p0];
    float4 bgv = *(const float4*)&bufg[gi*160 + 32 + n0];
    float yw[4]={ywv.x,ywv.y,ywv.z,ywv.w}, bw[4]={bwv.x,bwv.y,bwv.z,bwv.w};
    float yg[4]={ygv.x,ygv.y,ygv.z,ygv.w}, bg[4]={bgv.x,bgv.y,bgv.z,bgv.w};
    #pragma unroll
    for (int i=0;i<4;i++)
      #pragma unroll
      for (int j=0;j<4;j++)
        acc[i][j] += yw[i]*bw[j] - yg[i]*bg[j];
  }
  size_t fb = (size_t)(b*TWIN + t)*4096;
  #pragma unroll
  for (int i=0;i<4;i++)
    #pragma unroll
    for (int j=0;j<4;j++)
      feat[fb + (p0+i)*128 + n0+j] += acc[i][j];
}

// out[bt][k] = feat[bt] . cls_w[k] + cls_b[k]; one wave per (bt,k)
__global__ __launch_bounds__(256) void k_classifier(const float* __restrict__ feat,
    const float* __restrict__ cls_w, const float* __restrict__ cls_b,
    float* __restrict__ out){
  int bt = blockIdx.x;
  int wave = threadIdx.x >> 6, lane = threadIdx.x & 63;
  int k = blockIdx.y*4 + wave;
  if (k >= 100) return;
  const float* f  = feat  + (size_t)bt*4096;
  const float* wr = cls_w + (size_t)k*4096;
  float s = 0.f;
  #pragma unroll
  for (int j0 = 0; j0 < 4096; j0 += 256){
    int j = j0 + lane*4;
    float4 fv = *(const float4*)(f + j);
    float4 wv = *(const float4*)(wr + j);
    s += fv.x*wv.x + fv.y*wv.y + fv.z*wv.z + fv.w*wv.w;
  }
  #pragma unroll
  for (int off=32; off>0; off>>=1) s += __shfl_down(s, off, 64);
  if (lane==0) out[bt*100 + k] = s + cls_b[k];
}

extern "C" void kernel_launch(void* const* d_in, const int* in_sizes, int n_in,
                              void* d_out, int out_size, void* d_ws, size_t ws_size,
                              hipStream_t stream){
  const float* inputs    = (const float*)d_in[0];
  const float* in_proj_w = (const float*)d_in[1];
  const float* conv_w    = (const float*)d_in[2];
  const float* conv_b    = (const float*)d_in[3];
  const float* dt_bias   = (const float*)d_in[4];
  const float* A_log     = (const float*)d_in[5];
  const float* cls_w     = (const float*)d_in[6];
  const float* cls_b     = (const float*)d_in[7];
  float* out = (float*)d_out;

  float* xg            = (float*)d_ws;                          // MTOT*192 f32
  unsigned short* projh= (unsigned short*)(xg + (size_t)MTOT*DMODEL); // MTOT*896 bf16
  float* dtraw         = (float*)(projh + (size_t)MTOT*NCC);    // MTOT*24 f32
  float* wbuf          = dtraw + (size_t)MTOT*NH;               // MTOT*24 f32
  unsigned short* xh   = (unsigned short*)(wbuf + (size_t)MTOT*NH); // MTOT*192 bf16
  unsigned short* wh   = xh + (size_t)MTOT*DMODEL;              // NCC*192 bf16
  float* yB            = (float*)(wh + (size_t)NCC*DMODEL);     // MTOT*160 f32
  float* partial       = yB + (size_t)MTOT*160;                 // 512*4096 f32
  float* feat          = partial + (size_t)512*4096;            // 128*4096 f32
  size_t need = (size_t)((char*)(feat + (size_t)128*4096) - (char*)d_ws);
  if (ws_size < need) return;

  k_build_xg   <<<((MTOT+NCC)*DMODEL + 255)/256, 256, 0, stream>>>(inputs, in_proj_w, xg, xh, wh);
  k_gemm_mfma  <<<dim3(MTOT/128, NCC/128), 256, 0, stream>>>(xh, wh, projh);
  k_gemm_dt    <<<dim3(MTOT/64, 1), 256, 0, stream>>>(xg, in_proj_w, dtraw);
  k_scan_w     <<<dim3(NH, BATCH), 256, 0, stream>>>(dtraw, dt_bias, A_log, wbuf);
  k_fold       <<<dim3(GLEN/8/4, BATCH), 256, 0, stream>>>(projh, conv_w, conv_b, wbuf, yB);
  k_partial    <<<dim3(BATCH*TWIN, 4), 256, 0, stream>>>(yB, partial);
  k_suffix     <<<dim3(16, BATCH), 256, 0, stream>>>(partial, feat);
  k_correct    <<<dim3(TWIN-1, BATCH), 256, 0, stream>>>(projh, conv_w, conv_b, wbuf, feat);
  k_classifier <<<dim3(BATCH*TWIN, 25), 256, 0, stream>>>(feat, cls_w, cls_b, out);
}